// Round 15
// baseline (28.760 us; speedup 1.0000x reference)
//
#include <hip/hip_runtime.h>
#include <hip/hip_bf16.h>

#define EPS 1e-8f

#define BB 16
#define CC 256
#define TT 512
#define LL 4096
#define KC  32    // t-chunk
#define TCB 128   // c-tile
#define TLB 32    // l-tile (small -> 4096 blocks = 4 residency rounds)
#define XR  40    // ws row stride in ushorts

typedef __attribute__((ext_vector_type(8))) short short8;
typedef __attribute__((ext_vector_type(4))) float f32x4;

__device__ __forceinline__ unsigned short bfbits(float f) {
    __hip_bfloat16 h = __float2bfloat16(f);
    return *(unsigned short*)&h;
}
__device__ __forceinline__ unsigned int pack2(float lo, float hi) {
    return (unsigned int)bfbits(lo) | ((unsigned int)bfbits(hi) << 16);
}

// ---------------------------------------------------------------------------
// Kernel A (tiny): per-batch scan -> global tables cen/nh/rad (L2-hot).
// ---------------------------------------------------------------------------
__global__ __launch_bounds__(512)
void scan_kernel(const float* __restrict__ w,
                 const float* __restrict__ sigma_scale,
                 float* __restrict__ cenG,
                 float* __restrict__ nhG,
                 float* __restrict__ radG) {
    const int b = blockIdx.x;
    const int t = threadIdx.x;       // 512
    const int lane = t & 63;
    const int wid  = t >> 6;
    __shared__ float part[8], offs[8];

    const float wv = w[b * TT + t];
    float v = wv;
#pragma unroll
    for (int o = 1; o < 64; o <<= 1) {
        float u = __shfl_up(v, o);
        if (lane >= o) v += u;
    }
    if (lane == 63) part[wid] = v;
    __syncthreads();
    if (t == 0) {
        float run = 0.0f;
#pragma unroll
        for (int i = 0; i < 8; ++i) { offs[i] = run; run += part[i]; }
    }
    __syncthreads();
    const float cum = offs[wid] + v;
    const float ss  = sigma_scale[0];
    const float sg  = wv * ss;
    cenG[b * TT + t] = cum - 0.5f * wv;
    nhG[b * TT + t]  = -0.5f / (sg * sg + EPS);
    radG[b * TT + t] = 6.5f * sg + 1.0f;   // cut terms <= e^-21 ~ 6.9e-10
}

// ---------------------------------------------------------------------------
// Kernel B: banded fused GEMM, 128c x 32l per block, 4096 blocks (4 rounds).
// Prologue: band-find from global cen/rad (L2). No LDS tables.
// Chunk loop (R7-proven): EXPW(next) double-buffered; MFMA(cur); 1 barrier.
// EXPW reads cen/nh/x_mask 4-t slices straight from L2.
// Denominator: per-thread p over (l, t-slice) -> shfl over lane&7 -> dsum.
// ---------------------------------------------------------------------------

#define EXPW(tc_, buf_)                                                         \
    {                                                                           \
        const int t0 = (tc_) + tg * 4;                                          \
        const float4 cv = *(const float4*)&cenG[bTT + t0];                      \
        const float4 nv = *(const float4*)&nhG[bTT + t0];                       \
        const float4 xk = *(const float4*)&x_mask[bTT + t0];                    \
        const float posf = (float)(l0 + l_loc);                                 \
        float mu, e0, e1, e2, e3;                                               \
        mu = posf - cv.x; e0 = __expf(mu * mu * nv.x);                          \
        mu = posf - cv.y; e1 = __expf(mu * mu * nv.y);                          \
        mu = posf - cv.z; e2 = __expf(mu * mu * nv.z);                          \
        mu = posf - cv.w; e3 = __expf(mu * mu * nv.w);                          \
        p += (e0 + e1) + (e2 + e3);                                             \
        uint2 pk;                                                               \
        pk.x = pack2(e0 * xk.x, e1 * xk.y);                                     \
        pk.y = pack2(e2 * xk.z, e3 * xk.w);                                     \
        *(uint2*)&ws[buf_][l_loc][tg * 4] = pk;                                 \
    }

#define AFRAG(AF, crow_, tc_)                                                   \
    {                                                                           \
        const float* xp = &x[xbase + (size_t)(crow_) * TT + (tc_) + lg * 8];    \
        const float4 a0 = *(const float4*)xp;                                   \
        const float4 a1 = *(const float4*)(xp + 4);                             \
        uint4 ap;                                                               \
        ap.x = pack2(a0.x, a0.y);                                               \
        ap.y = pack2(a0.z, a0.w);                                               \
        ap.z = pack2(a1.x, a1.y);                                               \
        ap.w = pack2(a1.z, a1.w);                                               \
        AF = *(short8*)&ap;                                                     \
    }

#define MFMA_STEP(buf_, tc_)                                                    \
    {                                                                           \
        short8 af0, af1;                                                        \
        AFRAG(af0, wid * 32 + lq, tc_);                                         \
        AFRAG(af1, wid * 32 + 16 + lq, tc_);                                    \
        _Pragma("unroll")                                                       \
        for (int n = 0; n < 2; ++n) {                                           \
            const short8 bfr = *(const short8*)&ws[buf_][n * 16 + lq][lg * 8];  \
            acc0[n] = __builtin_amdgcn_mfma_f32_16x16x32_bf16(af0, bfr, acc0[n], 0, 0, 0); \
            acc1[n] = __builtin_amdgcn_mfma_f32_16x16x32_bf16(af1, bfr, acc1[n], 0, 0, 0); \
        }                                                                       \
    }

__global__ __launch_bounds__(256, 4)
void fused_kernel(const float* __restrict__ x,
                  const float* __restrict__ x_mask,
                  const float* __restrict__ y_mask,
                  const float* __restrict__ cenG,
                  const float* __restrict__ nhG,
                  const float* __restrict__ radG,
                  float* __restrict__ out) {
    __shared__ unsigned short ws[2][TLB][XR];   // 5.0 KB
    __shared__ float dsum[TLB], sscale[TLB];
    __shared__ int tmin_s, tmax_s;

    // XCD-chunked bijective swizzle: 4096 blocks, XCD k -> batches 2k,2k+1.
    const int gid = blockIdx.x;
    const int lid = (gid & 7) * 512 + (gid >> 3);
    const int b   = lid >> 8;
    const int rr  = lid & 255;
    const int l0  = (rr >> 1) * TLB;
    const int c0  = (rr & 1) * TCB;

    const int tid  = threadIdx.x;
    const int lane = tid & 63;
    const int wid  = tid >> 6;
    const int lq   = lane & 15;
    const int lg   = lane >> 4;
    const int l_loc = tid >> 3;   // EXPW: 32 l's, 8 threads each
    const int tg    = tid & 7;    // EXPW: 8 t-slices of 4
    const int bTT  = b * TT;
    const size_t xbase = (size_t)(b * CC + c0) * TT;

    if (tid == 0) { tmin_s = TT; tmax_s = -1; }
    __syncthreads();

    // ---- band-find from global tables (L2-hot) ----
    const float l0f = (float)l0;
    const float l1f = l0f + (float)(TLB - 1);
#pragma unroll
    for (int i = 0; i < 2; ++i) {
        const int tt = tid + 256 * i;
        const float cen = cenG[bTT + tt];
        const float rad = radG[bTT + tt];
        if (cen + rad >= l0f && cen - rad <= l1f) {
            atomicMin(&tmin_s, tt);
            atomicMax(&tmax_s, tt);
        }
    }
    __syncthreads();

    int nch = 0, tlo = 0;
    if (tmax_s >= 0) {
        nch = (tmax_s - tmin_s + KC) / KC;      // ceil((tmax-tmin+1)/KC)
        tlo = tmin_s;
        if (tlo + nch * KC > TT) tlo = TT - nch * KC;  // keep window in [0,TT)
    }

    f32x4 acc0[2], acc1[2];
#pragma unroll
    for (int n = 0; n < 2; ++n) { acc0[n] = (f32x4)0.0f; acc1[n] = (f32x4)0.0f; }
    float p = 0.0f;

    // ---- banded pipelined GEMM ----
    if (nch > 0) {
        EXPW(tlo, 0);
        __syncthreads();
        for (int i = 0; i < nch; ++i) {
            const int cur = i & 1;
            if (i + 1 < nch) EXPW(tlo + (i + 1) * KC, cur ^ 1);
            MFMA_STEP(cur, tlo + i * KC);
            __syncthreads();
        }
    }

    // ---- denominator: reduce p over the 8 t-slice lanes (lane&7) ----
    p += __shfl_xor(p, 1);
    p += __shfl_xor(p, 2);
    p += __shfl_xor(p, 4);
    if ((lane & 7) == 0) dsum[wid * 8 + (lane >> 3)] = p;
    __syncthreads();
    if (tid < TLB)
        sscale[tid] = y_mask[b * LL + l0 + tid] / (dsum[tid] + EPS);
    __syncthreads();

    // ---- epilogue: each out row is exactly one 128B line ----
    const float sc0 = sscale[lq];
    const float sc1 = sscale[16 + lq];
    const size_t obase = (size_t)(b * CC + c0) * LL + l0;
#pragma unroll
    for (int r = 0; r < 4; ++r) {
        const int rowA = wid * 32 + lg * 4 + r;
        float* opA = &out[obase + (size_t)rowA * LL];
        opA[lq]      = acc0[0][r] * sc0;
        opA[16 + lq] = acc0[1][r] * sc1;
        float* opB = opA + 16 * LL;
        opB[lq]      = acc1[0][r] * sc0;
        opB[16 + lq] = acc1[1][r] * sc1;
    }
}

extern "C" void kernel_launch(void* const* d_in, const int* in_sizes, int n_in,
                              void* d_out, int out_size, void* d_ws, size_t ws_size,
                              hipStream_t stream) {
    const float* x           = (const float*)d_in[0];
    const float* w           = (const float*)d_in[1];
    const float* x_mask      = (const float*)d_in[2];
    const float* y_mask      = (const float*)d_in[3];
    const float* sigma_scale = (const float*)d_in[4];
    float* out = (float*)d_out;

    float* cenG = (float*)d_ws;
    float* nhG  = cenG + BB * TT;
    float* radG = nhG + BB * TT;

    hipLaunchKernelGGL(scan_kernel, dim3(BB), dim3(512), 0, stream,
                       w, sigma_scale, cenG, nhG, radG);
    hipLaunchKernelGGL(fused_kernel,
                       dim3((LL / TLB) * (CC / TCB) * BB), dim3(256), 0, stream,
                       x, x_mask, y_mask, cenG, nhG, radG, out);
}

// Round 17
// 26.436 us; speedup vs baseline: 1.0879x; 1.0879x over previous
//
#include <hip/hip_runtime.h>
#include <hip/hip_bf16.h>

#define EPS 1e-8f

#define BB 16
#define CC 256
#define TT 512
#define LL 4096
#define KC  32    // t-chunk
#define TCB 128   // c-tile
#define TLB 128   // block l-tile
#define SUB 32    // l-subtile (compute+store interleave unit)
#define XR  40    // ws row stride in ushorts

typedef __attribute__((ext_vector_type(8))) short short8;
typedef __attribute__((ext_vector_type(4))) float f32x4;

__device__ __forceinline__ unsigned short bfbits(float f) {
    __hip_bfloat16 h = __float2bfloat16(f);
    return *(unsigned short*)&h;
}
__device__ __forceinline__ unsigned int pack2(float lo, float hi) {
    return (unsigned int)bfbits(lo) | ((unsigned int)bfbits(hi) << 16);
}

// ---------------------------------------------------------------------------
// Single fused kernel. R14 base; l-tile processed as 4 x 32-l subtiles so
// each subtile's stores drain (async, no dependency) while the next subtile
// computes. Epilogue = R7-proven direct scalar stores (no LDS transpose).
//   phase 0: per-block redundant scan -> cen/nh/xm LDS tables
//   phase 1: 4 per-subtile band-finds (per-t radius 6.5*sigma+1, R15-proven)
//   phase 2: per subtile: double-buffered EXPW/MFMA chunks -> denom -> stores
// Block: 128c x 128l, 256 thr = 4 waves. Grid: 1024 = 4/CU x 256 CUs.
// ---------------------------------------------------------------------------

// 32l x 32t weight chunk: 4 exps/thread; l_loc=tid>>3, tg=tid&7
#define EXPW(tc_, buf_)                                                         \
    {                                                                           \
        const int t0 = (tc_) + tg * 4;                                          \
        const float4 cv = *(const float4*)&cen_s[t0];                           \
        const float4 nv = *(const float4*)&nh_s[t0];                            \
        const float4 xk = *(const float4*)&xm_s[t0];                            \
        const float posf = (float)(ls0 + l_loc);                                \
        float mu, e0, e1, e2, e3;                                               \
        mu = posf - cv.x; e0 = __expf(mu * mu * nv.x);                          \
        mu = posf - cv.y; e1 = __expf(mu * mu * nv.y);                          \
        mu = posf - cv.z; e2 = __expf(mu * mu * nv.z);                          \
        mu = posf - cv.w; e3 = __expf(mu * mu * nv.w);                          \
        p += (e0 + e1) + (e2 + e3);                                             \
        uint2 pk;                                                               \
        pk.x = pack2(e0 * xk.x, e1 * xk.y);                                     \
        pk.y = pack2(e2 * xk.z, e3 * xk.w);                                     \
        *(uint2*)&ws[buf_][l_loc][tg * 4] = pk;                                 \
    }

#define AFRAG(AF, crow_, tc_)                                                   \
    {                                                                           \
        const float* xp = &x[xbase + (size_t)(crow_) * TT + (tc_) + lg * 8];    \
        const float4 a0 = *(const float4*)xp;                                   \
        const float4 a1 = *(const float4*)(xp + 4);                             \
        uint4 ap;                                                               \
        ap.x = pack2(a0.x, a0.y);                                               \
        ap.y = pack2(a0.z, a0.w);                                               \
        ap.z = pack2(a1.x, a1.y);                                               \
        ap.w = pack2(a1.z, a1.w);                                               \
        AF = *(short8*)&ap;                                                     \
    }

#define MFMA_STEP(buf_, tc_)                                                    \
    {                                                                           \
        short8 af0, af1;                                                        \
        AFRAG(af0, wid * 32 + lq, tc_);                                         \
        AFRAG(af1, wid * 32 + 16 + lq, tc_);                                    \
        _Pragma("unroll")                                                       \
        for (int n = 0; n < 2; ++n) {                                           \
            const short8 bfr = *(const short8*)&ws[buf_][n * 16 + lq][lg * 8];  \
            acc0[n] = __builtin_amdgcn_mfma_f32_16x16x32_bf16(af0, bfr, acc0[n], 0, 0, 0); \
            acc1[n] = __builtin_amdgcn_mfma_f32_16x16x32_bf16(af1, bfr, acc1[n], 0, 0, 0); \
        }                                                                       \
    }

__global__ __launch_bounds__(256, 4)
void fused_kernel(const float* __restrict__ x,
                  const float* __restrict__ w,
                  const float* __restrict__ x_mask,
                  const float* __restrict__ y_mask,
                  const float* __restrict__ sigma_scale,
                  float* __restrict__ out) {
    __shared__ unsigned short ws[2][SUB][XR];        // 5.0 KB
    __shared__ float cen_s[TT], nh_s[TT], xm_s[TT];  // 6 KB
    __shared__ float dsum[SUB], sscale[SUB];
    __shared__ float part[4], offs[4];
    __shared__ int tmn[4], tmx[4];

    // XCD-chunked bijective swizzle: 1024 blocks, XCD k -> batches 2k,2k+1.
    const int gid = blockIdx.x;
    const int lid = (gid & 7) * 128 + (gid >> 3);
    const int b   = lid >> 6;
    const int rr  = lid & 63;
    const int l0  = (rr >> 1) * TLB;
    const int c0  = (rr & 1) * TCB;

    const int tid  = threadIdx.x;
    const int lane = tid & 63;
    const int wid  = tid >> 6;
    const int lq   = lane & 15;
    const int lg   = lane >> 4;
    const int l_loc = tid >> 3;   // EXPW: 32 l's, 8 threads each
    const int tg    = tid & 7;    // EXPW: 8 t-slices of 4
    const int bTT  = b * TT;
    const size_t xbase = (size_t)(b * CC + c0) * TT;

    if (tid < 4) { tmn[tid] = TT; tmx[tid] = -1; }

    // ---- phase 0: fused scan (2 w elems per thread) ----
    const int t2 = tid * 2;
    const float2 w2  = *(const float2*)&w[bTT + t2];
    const float2 xm2 = *(const float2*)&x_mask[bTT + t2];
    const float ss = sigma_scale[0];
    const float pairsum = w2.x + w2.y;
    float v = pairsum;
#pragma unroll
    for (int o = 1; o < 64; o <<= 1) {
        float u = __shfl_up(v, o);
        if (lane >= o) v += u;
    }
    if (lane == 63) part[wid] = v;
    __syncthreads();                       // (A) part[] + tmn/tmx init visible
    if (tid == 0) {
        float run = 0.0f;
#pragma unroll
        for (int i = 0; i < 4; ++i) { offs[i] = run; run += part[i]; }
    }
    __syncthreads();                       // (B) offs[] visible
    const float base = offs[wid] + v - pairsum;   // exclusive prefix
    const float cum1 = base + w2.x;
    const float cum2 = cum1 + w2.y;
    const float cenA = cum1 - 0.5f * w2.x;
    const float cenB = cum2 - 0.5f * w2.y;
    cen_s[t2]     = cenA;
    cen_s[t2 + 1] = cenB;
    const float sgA = w2.x * ss, sgB = w2.y * ss;
    nh_s[t2]     = -0.5f / (sgA * sgA + EPS);
    nh_s[t2 + 1] = -0.5f / (sgB * sgB + EPS);
    xm_s[t2]     = xm2.x;
    xm_s[t2 + 1] = xm2.y;

    // ---- phase 1: per-subtile band tests (cut terms <= e^-21) ----
    const float radA = 6.5f * sgA + 1.0f;
    const float radB = 6.5f * sgB + 1.0f;
#pragma unroll
    for (int s = 0; s < 4; ++s) {
        const float w0 = (float)(l0 + s * SUB);
        const float w1 = w0 + (float)(SUB - 1);
        if (cenA + radA >= w0 && cenA - radA <= w1) {
            atomicMin(&tmn[s], t2); atomicMax(&tmx[s], t2);
        }
        if (cenB + radB >= w0 && cenB - radB <= w1) {
            atomicMin(&tmn[s], t2 + 1); atomicMax(&tmx[s], t2 + 1);
        }
    }
    __syncthreads();                       // (C) tables + bands ready

    // ---- phase 2: subtile loop (compute + store interleaved) ----
    for (int s = 0; s < 4; ++s) {
        const int ls0 = l0 + s * SUB;
        int nch = 0, tlo = 0;
        if (tmx[s] >= 0) {
            tlo = tmn[s] & ~3;                       // keep float4 alignment
            nch = (tmx[s] - tlo + KC) / KC;
            const int maxlo = TT - nch * KC;
            if (tlo > maxlo) tlo = maxlo;            // window end <= TT
        }

        f32x4 acc0[2], acc1[2];
#pragma unroll
        for (int n = 0; n < 2; ++n) { acc0[n] = (f32x4)0.0f; acc1[n] = (f32x4)0.0f; }
        float p = 0.0f;

        if (nch > 0) {
            EXPW(tlo, 0);
            __syncthreads();
            for (int i = 0; i < nch; ++i) {
                const int cur = i & 1;
                if (i + 1 < nch) EXPW(tlo + (i + 1) * KC, cur ^ 1);
                MFMA_STEP(cur, tlo + i * KC);
                __syncthreads();
            }
        }

        // denominator: reduce p over the 8 t-slice lanes
        p += __shfl_xor(p, 1);
        p += __shfl_xor(p, 2);
        p += __shfl_xor(p, 4);
        if ((lane & 7) == 0) dsum[wid * 8 + (lane >> 3)] = p;
        __syncthreads();
        if (tid < SUB)
            sscale[tid] = y_mask[b * LL + ls0 + tid] / (dsum[tid] + EPS);
        __syncthreads();

        // epilogue for this subtile: direct scalar stores (R7-proven pattern)
        const float sc0 = sscale[lq];
        const float sc1 = sscale[16 + lq];
        const size_t obase = (size_t)(b * CC + c0) * LL + ls0;
#pragma unroll
        for (int r = 0; r < 4; ++r) {
            const int rowA = wid * 32 + lg * 4 + r;
            float* opA = &out[obase + (size_t)rowA * LL];
            opA[lq]      = acc0[0][r] * sc0;
            opA[16 + lq] = acc0[1][r] * sc1;
            float* opB = opA + 16 * LL;
            opB[lq]      = acc1[0][r] * sc0;
            opB[16 + lq] = acc1[1][r] * sc1;
        }
        __syncthreads();   // dsum/sscale/ws safe for next subtile
    }
}

extern "C" void kernel_launch(void* const* d_in, const int* in_sizes, int n_in,
                              void* d_out, int out_size, void* d_ws, size_t ws_size,
                              hipStream_t stream) {
    const float* x           = (const float*)d_in[0];
    const float* w           = (const float*)d_in[1];
    const float* x_mask      = (const float*)d_in[2];
    const float* y_mask      = (const float*)d_in[3];
    const float* sigma_scale = (const float*)d_in[4];
    float* out = (float*)d_out;

    hipLaunchKernelGGL(fused_kernel, dim3((LL / TLB) * (CC / TCB) * BB), dim3(256), 0, stream,
                       x, w, x_mask, y_mask, sigma_scale, out);
}

// Round 18
// 26.263 us; speedup vs baseline: 1.0951x; 1.0066x over previous
//
#include <hip/hip_runtime.h>
#include <hip/hip_bf16.h>

#define EPS 1e-8f

#define BB 16
#define CC 256
#define TT 512
#define LL 4096
#define KC  32    // t-chunk
#define TCB 128   // c-tile
#define TLB 128   // block l-tile
#define SUB 32    // l-subtile (compute+store interleave unit)
#define XR  40    // ws row stride in ushorts

typedef __attribute__((ext_vector_type(8))) short short8;
typedef __attribute__((ext_vector_type(4))) float f32x4;

__device__ __forceinline__ unsigned short bfbits(float f) {
    __hip_bfloat16 h = __float2bfloat16(f);
    return *(unsigned short*)&h;
}
__device__ __forceinline__ unsigned int pack2(float lo, float hi) {
    return (unsigned int)bfbits(lo) | ((unsigned int)bfbits(hi) << 16);
}

// ---------------------------------------------------------------------------
// Single fused kernel. R17 base with DOUBLE-BUFFERED per-subtile shared state
// (ws/dsum/sscale by s&1) and NO barrier after stores: subtile s's stores
// drain through HBM while subtile s+1 computes. Hazards resolve at s+2,
// >=2 barriers later.
//   phase 0: per-block redundant scan -> cen/nh/xm LDS tables
//   phase 1: 4 per-subtile band-finds (per-t radius 6.5*sigma+1)
//   phase 2: per subtile: double-buffered EXPW/MFMA chunks -> denom -> stores
// Block: 128c x 128l, 256 thr = 4 waves. Grid: 1024 = 4/CU x 256 CUs.
// ---------------------------------------------------------------------------

// 32l x 32t weight chunk: 4 exps/thread; l_loc=tid>>3, tg=tid&7
#define EXPW(tc_, set_, buf_)                                                   \
    {                                                                           \
        const int t0 = (tc_) + tg * 4;                                          \
        const float4 cv = *(const float4*)&cen_s[t0];                           \
        const float4 nv = *(const float4*)&nh_s[t0];                            \
        const float4 xk = *(const float4*)&xm_s[t0];                            \
        const float posf = (float)(ls0 + l_loc);                                \
        float mu, e0, e1, e2, e3;                                               \
        mu = posf - cv.x; e0 = __expf(mu * mu * nv.x);                          \
        mu = posf - cv.y; e1 = __expf(mu * mu * nv.y);                          \
        mu = posf - cv.z; e2 = __expf(mu * mu * nv.z);                          \
        mu = posf - cv.w; e3 = __expf(mu * mu * nv.w);                          \
        p += (e0 + e1) + (e2 + e3);                                             \
        uint2 pk;                                                               \
        pk.x = pack2(e0 * xk.x, e1 * xk.y);                                     \
        pk.y = pack2(e2 * xk.z, e3 * xk.w);                                     \
        *(uint2*)&ws[set_][buf_][l_loc][tg * 4] = pk;                           \
    }

#define AFRAG(AF, crow_, tc_)                                                   \
    {                                                                           \
        const float* xp = &x[xbase + (size_t)(crow_) * TT + (tc_) + lg * 8];    \
        const float4 a0 = *(const float4*)xp;                                   \
        const float4 a1 = *(const float4*)(xp + 4);                             \
        uint4 ap;                                                               \
        ap.x = pack2(a0.x, a0.y);                                               \
        ap.y = pack2(a0.z, a0.w);                                               \
        ap.z = pack2(a1.x, a1.y);                                               \
        ap.w = pack2(a1.z, a1.w);                                               \
        AF = *(short8*)&ap;                                                     \
    }

#define MFMA_STEP(set_, buf_, tc_)                                              \
    {                                                                           \
        short8 af0, af1;                                                        \
        AFRAG(af0, wid * 32 + lq, tc_);                                         \
        AFRAG(af1, wid * 32 + 16 + lq, tc_);                                    \
        _Pragma("unroll")                                                       \
        for (int n = 0; n < 2; ++n) {                                           \
            const short8 bfr = *(const short8*)&ws[set_][buf_][n * 16 + lq][lg * 8]; \
            acc0[n] = __builtin_amdgcn_mfma_f32_16x16x32_bf16(af0, bfr, acc0[n], 0, 0, 0); \
            acc1[n] = __builtin_amdgcn_mfma_f32_16x16x32_bf16(af1, bfr, acc1[n], 0, 0, 0); \
        }                                                                       \
    }

__global__ __launch_bounds__(256, 4)
void fused_kernel(const float* __restrict__ x,
                  const float* __restrict__ w,
                  const float* __restrict__ x_mask,
                  const float* __restrict__ y_mask,
                  const float* __restrict__ sigma_scale,
                  float* __restrict__ out) {
    __shared__ unsigned short ws[2][2][SUB][XR];     // 10.0 KB (set x chunkbuf)
    __shared__ float cen_s[TT], nh_s[TT], xm_s[TT];  // 6 KB
    __shared__ float dsum[2][SUB], sscale[2][SUB];
    __shared__ float part[4], offs[4];
    __shared__ int tmn[4], tmx[4];

    // XCD-chunked bijective swizzle: 1024 blocks, XCD k -> batches 2k,2k+1.
    const int gid = blockIdx.x;
    const int lid = (gid & 7) * 128 + (gid >> 3);
    const int b   = lid >> 6;
    const int rr  = lid & 63;
    const int l0  = (rr >> 1) * TLB;
    const int c0  = (rr & 1) * TCB;

    const int tid  = threadIdx.x;
    const int lane = tid & 63;
    const int wid  = tid >> 6;
    const int lq   = lane & 15;
    const int lg   = lane >> 4;
    const int l_loc = tid >> 3;   // EXPW: 32 l's, 8 threads each
    const int tg    = tid & 7;    // EXPW: 8 t-slices of 4
    const int bTT  = b * TT;
    const size_t xbase = (size_t)(b * CC + c0) * TT;

    if (tid < 4) { tmn[tid] = TT; tmx[tid] = -1; }

    // ---- phase 0: fused scan (2 w elems per thread) ----
    const int t2 = tid * 2;
    const float2 w2  = *(const float2*)&w[bTT + t2];
    const float2 xm2 = *(const float2*)&x_mask[bTT + t2];
    const float ss = sigma_scale[0];
    const float pairsum = w2.x + w2.y;
    float v = pairsum;
#pragma unroll
    for (int o = 1; o < 64; o <<= 1) {
        float u = __shfl_up(v, o);
        if (lane >= o) v += u;
    }
    if (lane == 63) part[wid] = v;
    __syncthreads();                       // (A) part[] + tmn/tmx init visible
    if (tid == 0) {
        float run = 0.0f;
#pragma unroll
        for (int i = 0; i < 4; ++i) { offs[i] = run; run += part[i]; }
    }
    __syncthreads();                       // (B) offs[] visible
    const float base = offs[wid] + v - pairsum;   // exclusive prefix
    const float cum1 = base + w2.x;
    const float cum2 = cum1 + w2.y;
    const float cenA = cum1 - 0.5f * w2.x;
    const float cenB = cum2 - 0.5f * w2.y;
    cen_s[t2]     = cenA;
    cen_s[t2 + 1] = cenB;
    const float sgA = w2.x * ss, sgB = w2.y * ss;
    nh_s[t2]     = -0.5f / (sgA * sgA + EPS);
    nh_s[t2 + 1] = -0.5f / (sgB * sgB + EPS);
    xm_s[t2]     = xm2.x;
    xm_s[t2 + 1] = xm2.y;

    // ---- phase 1: per-subtile band tests (cut terms <= e^-21) ----
    const float radA = 6.5f * sgA + 1.0f;
    const float radB = 6.5f * sgB + 1.0f;
#pragma unroll
    for (int s = 0; s < 4; ++s) {
        const float w0 = (float)(l0 + s * SUB);
        const float w1 = w0 + (float)(SUB - 1);
        if (cenA + radA >= w0 && cenA - radA <= w1) {
            atomicMin(&tmn[s], t2); atomicMax(&tmx[s], t2);
        }
        if (cenB + radB >= w0 && cenB - radB <= w1) {
            atomicMin(&tmn[s], t2 + 1); atomicMax(&tmx[s], t2 + 1);
        }
    }
    __syncthreads();                       // (C) tables + bands ready

    // ---- phase 2: subtile loop; stores drain during next subtile ----
    for (int s = 0; s < 4; ++s) {
        const int set = s & 1;
        const int ls0 = l0 + s * SUB;
        int nch = 0, tlo = 0;
        if (tmx[s] >= 0) {
            tlo = tmn[s] & ~3;                       // keep float4 alignment
            nch = (tmx[s] - tlo + KC) / KC;
            const int maxlo = TT - nch * KC;
            if (tlo > maxlo) tlo = maxlo;            // window end <= TT
        }

        f32x4 acc0[2], acc1[2];
#pragma unroll
        for (int n = 0; n < 2; ++n) { acc0[n] = (f32x4)0.0f; acc1[n] = (f32x4)0.0f; }
        float p = 0.0f;

        if (nch > 0) {
            EXPW(tlo, set, 0);
            __syncthreads();
            for (int i = 0; i < nch; ++i) {
                const int cur = i & 1;
                if (i + 1 < nch) EXPW(tlo + (i + 1) * KC, set, cur ^ 1);
                MFMA_STEP(set, cur, tlo + i * KC);
                __syncthreads();
            }
        }

        // denominator: reduce p over the 8 t-slice lanes
        p += __shfl_xor(p, 1);
        p += __shfl_xor(p, 2);
        p += __shfl_xor(p, 4);
        if ((lane & 7) == 0) dsum[set][wid * 8 + (lane >> 3)] = p;
        __syncthreads();                    // dsum[set] visible
        if (tid < SUB)
            sscale[set][tid] = y_mask[b * LL + ls0 + tid] / (dsum[set][tid] + EPS);
        __syncthreads();                    // sscale[set] visible

        // epilogue: direct scalar stores, NO trailing barrier -> async drain
        const float sc0 = sscale[set][lq];
        const float sc1 = sscale[set][16 + lq];
        const size_t obase = (size_t)(b * CC + c0) * LL + ls0;
#pragma unroll
        for (int r = 0; r < 4; ++r) {
            const int rowA = wid * 32 + lg * 4 + r;
            float* opA = &out[obase + (size_t)rowA * LL];
            opA[lq]      = acc0[0][r] * sc0;
            opA[16 + lq] = acc0[1][r] * sc1;
            float* opB = opA + 16 * LL;
            opB[lq]      = acc1[0][r] * sc0;
            opB[16 + lq] = acc1[1][r] * sc1;
        }
        // no __syncthreads here: ws/dsum/sscale for s+1 use the other set;
        // this set is rewritten only at s+2, beyond >=2 barriers.
    }
}

extern "C" void kernel_launch(void* const* d_in, const int* in_sizes, int n_in,
                              void* d_out, int out_size, void* d_ws, size_t ws_size,
                              hipStream_t stream) {
    const float* x           = (const float*)d_in[0];
    const float* w           = (const float*)d_in[1];
    const float* x_mask      = (const float*)d_in[2];
    const float* y_mask      = (const float*)d_in[3];
    const float* sigma_scale = (const float*)d_in[4];
    float* out = (float*)d_out;

    hipLaunchKernelGGL(fused_kernel, dim3((LL / TLB) * (CC / TCB) * BB), dim3(256), 0, stream,
                       x, w, x_mask, y_mask, sigma_scale, out);
}